// Round 8
// baseline (106686.719 us; speedup 1.0000x reference)
//
#include <hip/hip_runtime.h>
#include <cstddef>

#define LRC 0.001f
#define DEC 0.99f

typedef float f32x4 __attribute__((ext_vector_type(4)));

// ---------------- workspace layout (float offsets) ----------------
static const size_t OFF_H1F = 376832;       // 2048
static const size_t OFF_H2F = 380928;
static const size_t OFF_H2Q = 382976;
static const size_t OFF_H3F = 385024;
static const size_t OFF_H3Q = 387072;
static const size_t OFF_D4F = 389120;       // 768
static const size_t OFF_D4Q = 389888;       // 768
static const size_t OFF_D3F = 390656;       // 2048
static const size_t OFF_D3Q = 392704;
static const size_t OFF_D2F = 394752;
static const size_t OFF_D2Q = 396800;
static const size_t OFF_SL4 = 398848;       // 256
static const size_t OFF_D1Q = 400896;       // 2048
static const size_t OFF_NSQ = 402944;       // 16 (contiguous with SL3,SL2,SL1 below)
static const size_t OFF_SL3 = 402960;       // 256
static const size_t OFF_SL2 = 403216;
static const size_t OFF_SL1 = 403472;       // ends 403728
static const size_t OFF_MSUM = 403732;      // [32][768]
static const size_t OFF_HA  = 428308;       // barrier + census state during scan
static const size_t OFF_HB  = 2525460;      // GEMM scratch; start doubles as XCD stage during scan
static const size_t OFF_STG = 2525460;      // per-XCD stage base (8 x 32768 floats)

// LDS map (float indices)
#define ST0  0
#define ST1  2048
#define ST2  4096
#define ST3  6144
#define SD4F 8192
#define SD4Q 8960
#define SRED 9728
#define SCND 10240
#define SBUF 10244
#define SCOND 10245
#define SB4  10248
#define SSQ  10256
#define SWRP 10264
#define SWRQ 10288

// ---------------- coherent (L3) access helpers ----------------
__device__ __forceinline__ float clf(const float* p) {
    return __hip_atomic_load(p, __ATOMIC_RELAXED, __HIP_MEMORY_SCOPE_AGENT);
}
__device__ __forceinline__ void csf(float* p, float v) {
    __hip_atomic_store(p, v, __ATOMIC_RELAXED, __HIP_MEMORY_SCOPE_AGENT);
}
__device__ __forceinline__ f32x4 cl4(const float* p) {
    f32x4 r;
    asm volatile("global_load_dwordx4 %0, %1, off sc0 sc1" : "=&v"(r) : "v"(p) : "memory");
    return r;
}
__device__ __forceinline__ void vwait() {
    asm volatile("s_waitcnt vmcnt(0)" ::: "memory");
    __builtin_amdgcn_sched_barrier(0);   // rule #18: pin uses after the waitcnt
}
// ---------------- XCD-local (L2-served) DATA helpers ----------------
// Writer and reader are guaranteed same-XCD (census by HW_REG_XCC_ID), so the
// shared per-XCD L2 is the point of coherence for these accesses. sc0 bypasses L1.
__device__ __forceinline__ f32x4 s4(const float* p) {          // batch, then vwait()
    f32x4 r;
    asm volatile("global_load_dwordx4 %0, %1, off sc0" : "=&v"(r) : "v"(p) : "memory");
    return r;
}
__device__ __forceinline__ float s1(const float* p) {          // self-waiting scalar
    float r;
    asm volatile("global_load_dword %0, %1, off sc0\n\t"
                 "s_waitcnt vmcnt(0)" : "=&v"(r) : "v"(p) : "memory");
    return r;
}

__device__ __forceinline__ float dot4(const f32x4 a, const f32x4 b) {
    float s = a.x * b.x; s += a.y * b.y; s += a.z * b.z; s += a.w * b.w; return s;
}
__device__ __forceinline__ int swz(int p) { return p ^ (((p >> 5) & 7) << 2); }

__device__ __forceinline__ void updc(f32x4& wv, const f32x4 a, float dq) {
    wv.x = DEC * wv.x - (LRC * a.x) * dq;
    wv.y = DEC * wv.y - (LRC * a.y) * dq;
    wv.z = DEC * wv.z - (LRC * a.z) * dq;
    wv.w = DEC * wv.w - (LRC * a.w) * dq;
}
__device__ __forceinline__ void updr(f32x4& wv, float u, const f32x4 dv) {
    wv.x = DEC * wv.x - u * dv.x;
    wv.y = DEC * wv.y - u * dv.y;
    wv.z = DEC * wv.z - u * dv.z;
    wv.w = DEC * wv.w - u * dv.w;
}

__device__ __forceinline__ float block_reduce_512s(float v, float* red) {
    int t = threadIdx.x;
    red[t] = v;
    __syncthreads();
    for (int st = 256; st > 0; st >>= 1) {
        if (t < st) red[t] += red[t + st];
        __syncthreads();
    }
    float r = red[0];
    __syncthreads();
    return r;
}

// ---- global grid barrier, fence-free (proven rounds 5/7) ----
__device__ __forceinline__ void gbar(unsigned* bar) {
    asm volatile("s_waitcnt vmcnt(0) lgkmcnt(0)" ::: "memory");
    __syncthreads();
    if (threadIdx.x == 0) {
        unsigned g = __hip_atomic_load(bar, __ATOMIC_RELAXED, __HIP_MEMORY_SCOPE_AGENT);
        asm volatile("s_waitcnt vmcnt(0)" ::: "memory");
        unsigned* grp = bar + 64 + ((blockIdx.x >> 4) << 5);
        bool released = false;
        if (__hip_atomic_fetch_add(grp, 1u, __ATOMIC_RELAXED, __HIP_MEMORY_SCOPE_AGENT) == 15u) {
            if (__hip_atomic_fetch_add(bar + 32, 1u, __ATOMIC_RELAXED, __HIP_MEMORY_SCOPE_AGENT) == 15u) {
#pragma unroll
                for (int i = 0; i < 16; ++i)
                    __hip_atomic_store(bar + 64 + (i << 5), 0u, __ATOMIC_RELAXED, __HIP_MEMORY_SCOPE_AGENT);
                __hip_atomic_store(bar + 32, 0u, __ATOMIC_RELAXED, __HIP_MEMORY_SCOPE_AGENT);
                __hip_atomic_store(bar, g + 1u, __ATOMIC_RELEASE, __HIP_MEMORY_SCOPE_AGENT);
                released = true;
            }
        }
        if (!released) {
            while (__hip_atomic_load(bar, __ATOMIC_RELAXED, __HIP_MEMORY_SCOPE_AGENT) == g)
                __builtin_amdgcn_s_sleep(2);
            (void)__hip_atomic_load(bar, __ATOMIC_ACQUIRE, __HIP_MEMORY_SCOPE_AGENT);
        }
    }
    __syncthreads();
}

// ---- XCD-local barrier over the m blocks on this XCD ----
// ALL sync ops agent-scope (L1-bypassed, coherence-point) — round-6's hang was a
// workgroup-scope polling load that could be served by stale L1.
__device__ __forceinline__ void lbar(unsigned* lg, unsigned* la, unsigned m) {
    asm volatile("s_waitcnt vmcnt(0) lgkmcnt(0)" ::: "memory");   // drain stage stores into L2
    __syncthreads();
    if (threadIdx.x == 0) {
        unsigned g = __hip_atomic_load(lg, __ATOMIC_RELAXED, __HIP_MEMORY_SCOPE_AGENT);
        asm volatile("s_waitcnt vmcnt(0)" ::: "memory");          // g resolved before arrive
        if (__hip_atomic_fetch_add(la, 1u, __ATOMIC_RELAXED, __HIP_MEMORY_SCOPE_AGENT) == m - 1u) {
            __hip_atomic_store(la, 0u, __ATOMIC_RELAXED, __HIP_MEMORY_SCOPE_AGENT);
            __hip_atomic_store(lg, g + 1u, __ATOMIC_RELEASE, __HIP_MEMORY_SCOPE_AGENT);
        } else {
            while (__hip_atomic_load(lg, __ATOMIC_RELAXED, __HIP_MEMORY_SCOPE_AGENT) == g)
                __builtin_amdgcn_s_sleep(1);
            (void)__hip_atomic_load(lg, __ATOMIC_ACQUIRE, __HIP_MEMORY_SCOPE_AGENT);
        }
    }
    __syncthreads();
}

// ---- stagecopy: this XCD's blocks cooperatively copy master(L3) -> stage(local L2) ----
__device__ __forceinline__ void scpy1(const float* src, float* dst, unsigned n4,
                                      unsigned rank, unsigned m, int tid) {
    unsigned c = rank + m * (unsigned)tid;
    if (c < n4) {
        f32x4 v;
        asm volatile("global_load_dwordx4 %0, %1, off sc0 sc1\n\t"
                     "s_waitcnt vmcnt(0)"
                     : "=&v"(v) : "v"(src + 4u * c) : "memory");
        asm volatile("global_store_dwordx4 %0, %1, off sc0"
                     :: "v"(dst + 4u * c), "v"(v) : "memory");
    }
}

__global__ __launch_bounds__(1024) void k_zero(unsigned* __restrict__ bar) {
    int t = threadIdx.x;
    bar[t] = 0u; bar[t + 1024] = 0u; bar[t + 2048] = 0u; bar[t + 3072] = 0u;
}

#define L3M(M) M(0) M(1) M(2)
#define L8M(M) M(0) M(1) M(2) M(3) M(4) M(5) M(6) M(7)
#define LDS_SW(buf, i) (*(const f32x4*)(smem + (buf) + swz(32 * lane + 4 * (i))))
#define LDS_D4(buf, i) (*(const f32x4*)(smem + (buf) + 12 * lane + 4 * (i)))

// ---------- the entire TTT scan: register weights + XCD-staged broadcasts ----------
__global__ __attribute__((amdgpu_flat_work_group_size(512, 512), amdgpu_waves_per_eu(2, 2)))
void k_scan(const float* __restrict__ x,
            float* __restrict__ W1g, float* __restrict__ b1g,
            float* __restrict__ W2g, float* __restrict__ b2g,
            float* __restrict__ W3g, float* __restrict__ b3g,
            float* __restrict__ W4g, float* __restrict__ b4g,
            float* __restrict__ wsf,
            const int* __restrict__ flag) {
    if (*flag == 0) return;
    __shared__ __align__(16) float smem[16896];
    unsigned* bar = (unsigned*)(wsf + OFF_HA);
    const int b = blockIdx.x, tid = threadIdx.x;
    const int w = tid >> 6, lane = tid & 63;
    const int jw = 8 * b + w;
    const int c3 = 3 * b;
    const int t4 = tid * 4;

    // ---- physical XCD id + census (agent-scope atomics; values L2-local by construction) ----
    unsigned xcc;
    asm volatile("s_getreg_b32 %0, hwreg(HW_REG_XCC_ID)" : "=s"(xcc));
    xcc &= 7u;
    unsigned* cns  = bar + 1024 + xcc * 16;
    unsigned* lgen = bar + 2048 + xcc * 16;
    unsigned* larr = bar + 3072 + xcc * 16;
    float* stg = wsf + (OFF_STG - OFF_H1F) + (size_t)xcc * 32768;   // stg[master_off] = stage copy
    unsigned* smU = (unsigned*)smem;
    if (tid == 0) smU[0] = __hip_atomic_fetch_add(cns, 1u, __ATOMIC_RELAXED, __HIP_MEMORY_SCOPE_AGENT);
    gbar(bar);
    if (tid == 0) smU[1] = __hip_atomic_load(cns, __ATOMIC_RELAXED, __HIP_MEMORY_SCOPE_AGENT);
    __syncthreads();
    const unsigned rank = smU[0];
    const unsigned m = smU[1];
    __syncthreads();

    // ---- named register shards ----
    f32x4 w1c0, w1c1, w1c2;
    f32x4 w2c0, w2c1, w2c2, w2c3, w2c4, w2c5, w2c6, w2c7;
    f32x4 w3c0, w3c1, w3c2, w3c3, w3c4, w3c5, w3c6, w3c7;
    f32x4 w4c0, w4c1, w4c2;
    f32x4 w4r0, w4r1, w4r2;
    f32x4 w2r0, w2r1, w2r2, w2r3, w2r4, w2r5, w2r6, w2r7;
    f32x4 w3r0, w3r1, w3r2, w3r3, w3r4, w3r5, w3r6, w3r7;

#define LD_COL(dst, Wg, ld, row0, col) { f32x4 t; \
    t.x = Wg[(size_t)((row0) + 0) * (ld) + (col)]; \
    t.y = Wg[(size_t)((row0) + 1) * (ld) + (col)]; \
    t.z = Wg[(size_t)((row0) + 2) * (ld) + (col)]; \
    t.w = Wg[(size_t)((row0) + 3) * (ld) + (col)]; dst = t; }
#define LDW1C(i) LD_COL(w1c##i, W1g, 2048, 12 * lane + 4 * (i), jw)
    L3M(LDW1C)
#undef LDW1C
#define LDW2C(i) LD_COL(w2c##i, W2g, 2048, 32 * lane + 4 * (i), jw)
    L8M(LDW2C)
#undef LDW2C
#define LDW3C(i) LD_COL(w3c##i, W3g, 2048, 32 * lane + 4 * (i), jw)
    L8M(LDW3C)
#undef LDW3C
#define LDW4C(i) LD_COL(w4c##i, W4g, 768, 4 * tid, c3 + (i))
    L3M(LDW4C)
#undef LDW4C
#define LDW4R(i) w4r##i = *(const f32x4*)(W4g + (size_t)jw * 768 + 12 * lane + 4 * (i));
    L3M(LDW4R)
#undef LDW4R
#define LDW2R(i) w2r##i = *(const f32x4*)(W2g + (size_t)jw * 2048 + 32 * lane + 4 * (i));
    L8M(LDW2R)
#undef LDW2R
#define LDW3R(i) w3r##i = *(const f32x4*)(W3g + (size_t)jw * 2048 + 32 * lane + 4 * (i));
    L8M(LDW3R)
#undef LDW3R
    if (tid == 0) smem[SBUF] = 0.f;

    for (int s = 0; s < 1024; ++s) {
        const float* xt = x + (size_t)s * 3072;
        const float* xprev = x + (size_t)(s > 0 ? s - 1 : 0) * 3072;

        // ===== Phase A: stage prev-step d1q/slots/nsq; cond; in-reg update; layer-1 fwd =====
        scpy1(wsf + OFF_D1Q, stg + OFF_D1Q, 512, rank, m, tid);
        scpy1(wsf + OFF_NSQ, stg + OFF_NSQ, 196, rank, m, tid);   // nsq+sl3+sl2+sl1 contiguous
        scpy1(wsf + OFF_SL4, stg + OFF_SL4, 64, rank, m, tid);
        lbar(lgen, larr, m);
        float cond = 0.f;
        if (s > 0) {
            if (w < 4) {
                const float* sl = stg + (w == 0 ? OFF_SL1 : w == 1 ? OFF_SL2 : w == 2 ? OFF_SL3 : OFF_SL4);
                float v = s1(sl + lane) + s1(sl + lane + 64) + s1(sl + lane + 128) + s1(sl + lane + 192);
#pragma unroll
                for (int off = 32; off > 0; off >>= 1) v += __shfl_down(v, off);
                if (lane == 0) smem[SCND + w] = v;
            }
            __syncthreads();
            if (tid == 0) {
                float nd1 = sqrtf(smem[SCND + 0]), nd2 = sqrtf(smem[SCND + 1]);
                float nd3 = sqrtf(smem[SCND + 2]), nd4 = sqrtf(smem[SCND + 3]);
                float nx = sqrtf(s1(stg + OFF_NSQ + 0));
                float nh1 = sqrtf(s1(stg + OFF_NSQ + 1));
                float nh2 = sqrtf(s1(stg + OFF_NSQ + 2));
                float nh3 = sqrtf(s1(stg + OFF_NSQ + 3));
                float surprise = nx * nd1 + nd1 + nh1 * nd2 + nd2 + nh2 * nd3 + nd3 + nh3 * nd4 + nd4;
                float bufold = smem[SBUF];
                float bufnew = (s == 1) ? surprise : (0.9f * bufold + 0.1f * surprise);
                smem[SBUF] = bufnew;
                smem[SCOND] = (bufnew > 0.1f) ? 1.f : 0.f;
            }
            __syncthreads();
            cond = smem[SCOND];
        }
        float b1j;
        if (cond != 0.f) {
            f32x4 a0 = s4(stg + OFF_H1F + t4);
            f32x4 a1 = s4(stg + OFF_H2Q + t4);
            f32x4 a2 = s4(stg + OFF_D2Q + t4);
            f32x4 a3 = s4(stg + OFF_D3Q + t4);
            f32x4 hq3 = s4(stg + OFF_H3Q + t4);
            f32x4 d4s = {0.f, 0.f, 0.f, 0.f};
            if (tid < 192) d4s = s4(stg + OFF_D4Q + t4);
            float d1qj = s1(stg + OFF_D1Q + jw);
            float h3qr = s1(stg + OFF_H3Q + jw);
            float h2qr = s1(stg + OFF_H2Q + jw);
            float ob1 = b1g[jw];
            f32x4 xp0 = *(const f32x4*)(xprev + 12 * lane);
            f32x4 xp1 = *(const f32x4*)(xprev + 12 * lane + 4);
            f32x4 xp2 = *(const f32x4*)(xprev + 12 * lane + 8);
            vwait();
            {
                int st = swz(t4);
                *(f32x4*)(smem + ST0 + st) = a0;
                *(f32x4*)(smem + ST1 + st) = a1;
                *(f32x4*)(smem + ST2 + st) = a2;
                *(f32x4*)(smem + ST3 + st) = a3;
            }
            if (tid < 192) *(f32x4*)(smem + SD4Q + t4) = d4s;
            __syncthreads();
            updc(w1c0, xp0, d1qj); updc(w1c1, xp1, d1qj); updc(w1c2, xp2, d1qj);
            {
                float d2qj = smem[ST2 + swz(jw)];
#define UPW2C(i) { f32x4 hf = LDS_SW(ST0, i); f32x4 af; \
                   af.x = DEC * hf.x; af.y = DEC * hf.y; af.z = DEC * hf.z; af.w = DEC * hf.w; \
                   updc(w2c##i, af, d2qj); }
                L8M(UPW2C)
#undef UPW2C
            }
            {
                float d3qj = smem[ST3 + swz(jw)];
#define UPW3C(i) { f32x4 hq = LDS_SW(ST1, i); updc(w3c##i, hq, d3qj); }
                L8M(UPW3C)
#undef UPW3C
            }
            {
                float vq0 = smem[SD4Q + c3 + 0];
                float vq1 = smem[SD4Q + c3 + 1];
                float vq2 = smem[SD4Q + c3 + 2];
                updc(w4c0, hq3, vq0); updc(w4c1, hq3, vq1); updc(w4c2, hq3, vq2);
            }
            {
                float u = LRC * h3qr;
#define UPW4R(i) { f32x4 dv = LDS_D4(SD4Q, i); updr(w4r##i, u, dv); }
                L3M(UPW4R)
#undef UPW4R
            }
            {
                float u = LRC * h2qr;
#define UPW3R(i) { f32x4 dv = LDS_SW(ST3, i); updr(w3r##i, u, dv); }
                L8M(UPW3R)
#undef UPW3R
            }
            {
                float u = LRC * (DEC * smem[ST0 + swz(jw)]);
#define UPW2R(i) { f32x4 dv = LDS_SW(ST2, i); updr(w2r##i, u, dv); }
                L8M(UPW2R)
#undef UPW2R
            }
            b1j = DEC * ob1 - LRC * d1qj;
            if (lane == 0) b1g[jw] = b1j;
        } else {
            b1j = b1g[jw];
        }
        {   // layer-1 forward: h1[jw]
            f32x4 x0 = *(const f32x4*)(xt + 12 * lane);
            f32x4 x1 = *(const f32x4*)(xt + 12 * lane + 4);
            f32x4 x2 = *(const f32x4*)(xt + 12 * lane + 8);
            float acc = dot4(w1c0, x0);
            acc += dot4(w1c1, x1);
            acc += dot4(w1c2, x2);
#pragma unroll
            for (int off = 32; off > 0; off >>= 1) acc += __shfl_down(acc, off);
            if (lane == 0) csf(wsf + OFF_H1F + jw, fmaxf(acc + b1j, 0.f));
        }
        gbar(bar);

        // ===== Phase B: layer 2 =====
        {
            scpy1(wsf + OFF_H1F, stg + OFF_H1F, 512, rank, m, tid);
            lbar(lgen, larr, m);
            f32x4 hv = s4(stg + OFF_H1F + t4);
            float ob2 = b2g[jw];
            float d2qjo = (cond != 0.f) ? s1(stg + OFF_D2Q + jw) : 0.f;
            vwait();
            *(f32x4*)(smem + ST0 + swz(t4)) = hv;
            float b2j = (cond != 0.f) ? (DEC * ob2 - LRC * d2qjo) : ob2;
            if (cond != 0.f && lane == 0) b2g[jw] = b2j;
            __syncthreads();
            float accP = 0.f, accQ = 0.f;
#define PHB(i) { const f32x4 hf = LDS_SW(ST0, i); f32x4 hq; \
                 hq.x = DEC * hf.x; hq.y = DEC * hf.y; hq.z = DEC * hf.z; hq.w = DEC * hf.w; \
                 accP += dot4(w2c##i, hf); accQ += dot4(w2c##i, hq); }
            L8M(PHB)
#undef PHB
#pragma unroll
            for (int off = 32; off > 0; off >>= 1) {
                accP += __shfl_down(accP, off);
                accQ += __shfl_down(accQ, off);
            }
            if (lane == 0) {
                csf(wsf + OFF_H2F + jw, fmaxf(accP + b2j, 0.f));
                csf(wsf + OFF_H2Q + jw, fmaxf(DEC * (accQ + b2j), 0.f));
            }
        }
        gbar(bar);

        // ===== Phase C: layer 3 =====
        {
            scpy1(wsf + OFF_H2F, stg + OFF_H2F, 512, rank, m, tid);
            scpy1(wsf + OFF_H2Q, stg + OFF_H2Q, 512, rank, m, tid);
            lbar(lgen, larr, m);
            f32x4 hfv = s4(stg + OFF_H2F + t4);
            f32x4 hqv = s4(stg + OFF_H2Q + t4);
            float ob3 = b3g[jw];
            float d3qjo = (cond != 0.f) ? s1(stg + OFF_D3Q + jw) : 0.f;
            vwait();
            {
                int st = swz(t4);
                *(f32x4*)(smem + ST0 + st) = hfv;
                *(f32x4*)(smem + ST1 + st) = hqv;
            }
            float b3j = (cond != 0.f) ? (DEC * ob3 - LRC * d3qjo) : ob3;
            if (cond != 0.f && lane == 0) b3g[jw] = b3j;
            __syncthreads();
            float accP = 0.f, accQ = 0.f;
#define PHC(i) { const f32x4 hf = LDS_SW(ST0, i); const f32x4 hq = LDS_SW(ST1, i); \
                 accP += dot4(w3c##i, hf); accQ += dot4(w3c##i, hq); }
            L8M(PHC)
#undef PHC
#pragma unroll
            for (int off = 32; off > 0; off >>= 1) {
                accP += __shfl_down(accP, off);
                accQ += __shfl_down(accQ, off);
            }
            if (lane == 0) {
                csf(wsf + OFF_H3F + jw, fmaxf(accP + b3j, 0.f));
                csf(wsf + OFF_H3Q + jw, fmaxf(DEC * (accQ + b3j), 0.f));
            }
        }
        gbar(bar);

        // ===== Phase D: layer 4 + d4 + slots/norms =====
        {
            scpy1(wsf + OFF_H3F, stg + OFF_H3F, 512, rank, m, tid);
            scpy1(wsf + OFF_H3Q, stg + OFF_H3Q, 512, rank, m, tid);
            lbar(lgen, larr, m);
            f32x4 hfv = s4(stg + OFF_H3F + t4);
            f32x4 hqv = s4(stg + OFF_H3Q + t4);
            float tv = 0.f;
            if (tid < 3) {
                float ob4 = b4g[c3 + tid];
                float d4qjo = (cond != 0.f) ? s1(stg + OFF_D4Q + c3 + tid) : 0.f;
                tv = xt[c3 + tid];
                float bn = (cond != 0.f) ? (DEC * ob4 - LRC * d4qjo) : ob4;
                if (cond != 0.f) b4g[c3 + tid] = bn;
                smem[SB4 + tid] = bn;
            }
            vwait();
            {
                int st = swz(t4);
                *(f32x4*)(smem + ST0 + st) = hfv;   // persists into phase E (gates)
                *(f32x4*)(smem + ST1 + st) = hqv;
            }
            float aP0 = dot4(w4c0, hfv), aP1 = dot4(w4c1, hfv), aP2 = dot4(w4c2, hfv);
            float aQ0 = dot4(w4c0, hqv), aQ1 = dot4(w4c1, hqv), aQ2 = dot4(w4c2, hqv);
#pragma unroll
            for (int off = 32; off > 0; off >>= 1) {
                aP0 += __shfl_down(aP0, off); aP1 += __shfl_down(aP1, off); aP2 += __shfl_down(aP2, off);
                aQ0 += __shfl_down(aQ0, off); aQ1 += __shfl_down(aQ1, off); aQ2 += __shfl_down(aQ2, off);
            }
            if (lane == 0) {
                smem[SWRP + w * 3 + 0] = aP0; smem[SWRP + w * 3 + 1] = aP1; smem[SWRP + w * 3 + 2] = aP2;
                smem[SWRQ + w * 3 + 0] = aQ0; smem[SWRQ + w * 3 + 1] = aQ1; smem[SWRQ + w * 3 + 2] = aQ2;
            }
            __syncthreads();
            if (tid < 3) {
                float zp = 0.f, zq = 0.f;
#pragma unroll
                for (int q = 0; q < 8; ++q) { zp += smem[SWRP + q * 3 + tid]; zq += smem[SWRQ + q * 3 + tid]; }
                float bn = smem[SB4 + tid];
                float d4f = 2.f * ((zp + bn) - tv) * (1.f / 768.f);
                float d4q = 2.f * (DEC * (zq + bn) - tv) * (1.f / 768.f);
                csf(wsf + OFF_D4F + c3 + tid, d4f);
                csf(wsf + OFF_D4Q + c3 + tid, d4q);
                smem[SSQ + tid] = d4f * d4f;
            }
            __syncthreads();
            if (tid == 0) csf(wsf + OFF_SL4 + b, smem[SSQ + 0] + smem[SSQ + 1] + smem[SSQ + 2]);
            if (b >= 1 && b <= 4) {
                float v = 0.f;
                if (b == 4) {
                    if (tid < 192) {
                        f32x4 xv = *(const f32x4*)(xt + t4);
                        v = xv.x * xv.x + xv.y * xv.y + xv.z * xv.z + xv.w * xv.w;
                    }
                } else {
                    const size_t soff = (b == 1) ? OFF_H1F : (b == 2) ? OFF_H2F : OFF_H3F;
                    f32x4 hh = s4(stg + soff + t4);
                    vwait();
                    v = hh.x * hh.x + hh.y * hh.y + hh.z * hh.z + hh.w * hh.w;
                }
                float sres = block_reduce_512s(v, smem + SRED);
                if (tid == 0) csf(wsf + OFF_NSQ + ((b == 4) ? 0 : b), sres);
            }
        }
        gbar(bar);

        // ===== Phase E: W4^T backward -> d3 =====
        {
            scpy1(wsf + OFF_D4F, stg + OFF_D4F, 192, rank, m, tid);
            scpy1(wsf + OFF_D4Q, stg + OFF_D4Q, 192, rank, m, tid);
            lbar(lgen, larr, m);
            f32x4 p4 = {0.f, 0.f, 0.f, 0.f}, q4 = {0.f, 0.f, 0.f, 0.f};
            if (tid < 192) {
                p4 = s4(stg + OFF_D4F + t4);
                q4 = s4(stg + OFF_D4Q + t4);
            }
            vwait();
            if (tid < 192) {
                *(f32x4*)(smem + SD4F + t4) = p4;
                *(f32x4*)(smem + SD4Q + t4) = q4;
            }
            __syncthreads();
            float accP = 0.f, accQ = 0.f;
#define PHE(i) { const f32x4 dP = LDS_D4(SD4F, i); const f32x4 dQ = LDS_D4(SD4Q, i); \
                 accP += dot4(w4r##i, dP); accQ += dot4(w4r##i, dQ); }
            L3M(PHE)
#undef PHE
#pragma unroll
            for (int off = 32; off > 0; off >>= 1) {
                accP += __shfl_down(accP, off);
                accQ += __shfl_down(accQ, off);
            }
            if (lane == 0) {
                float dp = (smem[ST0 + swz(jw)] > 0.f) ? accP : 0.f;
                float dq = (smem[ST1 + swz(jw)] > 0.f) ? DEC * accQ : 0.f;
                csf(wsf + OFF_D3F + jw, dp);
                csf(wsf + OFF_D3Q + jw, dq);
                smem[SSQ + w] = dp * dp;
            }
            __syncthreads();
            if (tid == 0) {
                float ss = 0.f;
#pragma unroll
                for (int q = 0; q < 8; ++q) ss += smem[SSQ + q];
                csf(wsf + OFF_SL3 + b, ss);
            }
        }
        gbar(bar);

        // ===== Phase F: W3^T backward -> d2 =====
        {
            scpy1(wsf + OFF_D3F, stg + OFF_D3F, 512, rank, m, tid);
            scpy1(wsf + OFF_D3Q, stg + OFF_D3Q, 512, rank, m, tid);
            lbar(lgen, larr, m);
            f32x4 fP = s4(stg + OFF_D3F + t4);
            f32x4 fQ = s4(stg + OFF_D3Q + t4);
            float h2fr = s1(stg + OFF_H2F + jw);
            float h2qr = s1(stg + OFF_H2Q + jw);
            vwait();
            {
                int st = swz(t4);
                *(f32x4*)(smem + ST2 + st) = fP;
                *(f32x4*)(smem + ST3 + st) = fQ;
            }
            __syncthreads();
            float accP = 0.f, accQ = 0.f;
#define PHF(i) { const f32x4 dP = LDS_SW(ST2, i); const f32x4 dQ = LDS_SW(ST3, i); \
                 accP += dot4(w3r##i, dP); accQ += dot4(w3r##i, dQ); }
            L8M(PHF)
#undef PHF
#pragma unroll
            for (int off = 32; off > 0; off >>= 1) {
                accP += __shfl_down(accP, off);
                accQ += __shfl_down(accQ, off);
            }
            if (lane == 0) {
                float dp = (h2fr > 0.f) ? accP : 0.f;
                float dq = (h2qr > 0.f) ? DEC * accQ : 0.f;
                csf(wsf + OFF_D2F + jw, dp);
                csf(wsf + OFF_D2Q + jw, dq);
                smem[SSQ + w] = dp * dp;
            }
            __syncthreads();
            if (tid == 0) {
                float ss = 0.f;
#pragma unroll
                for (int q = 0; q < 8; ++q) ss += smem[SSQ + q];
                csf(wsf + OFF_SL2 + b, ss);
            }
        }
        gbar(bar);

        // ===== Phase G: W2^T backward -> d1 =====
        {
            scpy1(wsf + OFF_D2F, stg + OFF_D2F, 512, rank, m, tid);
            scpy1(wsf + OFF_D2Q, stg + OFF_D2Q, 512, rank, m, tid);
            lbar(lgen, larr, m);
            f32x4 fP = s4(stg + OFF_D2F + t4);
            f32x4 fQ = s4(stg + OFF_D2Q + t4);
            float h1fr = s1(stg + OFF_H1F + jw);
            vwait();
            {
                int st = swz(t4);
                *(f32x4*)(smem + ST0 + st) = fP;
                *(f32x4*)(smem + ST1 + st) = fQ;
            }
            __syncthreads();
            float accP = 0.f, accQ = 0.f;
#define PHG(i) { const f32x4 dP = LDS_SW(ST0, i); const f32x4 dQ = LDS_SW(ST1, i); \
                 accP += dot4(w2r##i, dP); accQ += dot4(w2r##i, dQ); }
            L8M(PHG)
#undef PHG
#pragma unroll
            for (int off = 32; off > 0; off >>= 1) {
                accP += __shfl_down(accP, off);
                accQ += __shfl_down(accQ, off);
            }
            if (lane == 0) {
                float dp = (h1fr > 0.f) ? accP : 0.f;
                float h1qr = DEC * h1fr;
                float dq = (h1qr > 0.f) ? DEC * accQ : 0.f;
                csf(wsf + OFF_D1Q + jw, dq);
                smem[SSQ + w] = dp * dp;
            }
            __syncthreads();
            if (tid == 0) {
                float ss = 0.f;
#pragma unroll
                for (int q = 0; q < 8; ++q) ss += smem[SSQ + q];
                csf(wsf + OFF_SL1 + b, ss);
            }
        }
        gbar(bar);
    }

    // ===== Epilogue: apply final (step 1023) update to col-shards + biases (L3 masters) =====
    {
        if (w < 4) {
            const float* sl = wsf + (w == 0 ? OFF_SL1 : w == 1 ? OFF_SL2 : w == 2 ? OFF_SL3 : OFF_SL4);
            float v = clf(sl + lane) + clf(sl + lane + 64) + clf(sl + lane + 128) + clf(sl + lane + 192);
#pragma unroll
            for (int off = 32; off > 0; off >>= 1) v += __shfl_down(v, off);
            if (lane == 0) smem[SCND + w] = v;
        }
        __syncthreads();
        if (tid == 0) {
            float nd1 = sqrtf(smem[SCND + 0]), nd2 = sqrtf(smem[SCND + 1]);
            float nd3 = sqrtf(smem[SCND + 2]), nd4 = sqrtf(smem[SCND + 3]);
            float nx = sqrtf(clf(wsf + OFF_NSQ + 0));
            float nh1 = sqrtf(clf(wsf + OFF_NSQ + 1));
            float nh2 = sqrtf(clf(wsf + OFF_NSQ + 2));
            float nh3 = sqrtf(clf(wsf + OFF_NSQ + 3));
            float surprise = nx * nd1 + nd1 + nh1 * nd2 + nd2 + nh2 * nd3 + nd3 + nh3 * nd4 + nd4;
            float bufnew = 0.9f * smem[SBUF] + 0.1f * surprise;
            smem[SCOND] = (bufnew > 0.1f) ? 1.f : 0.f;
        }
        __syncthreads();
        if (smem[SCOND] != 0.f) {
            const float* xpE = x + (size_t)1023 * 3072;
            f32x4 a0 = cl4(wsf + OFF_H1F + t4);
            f32x4 a1 = cl4(wsf + OFF_H2Q + t4);
            f32x4 hq3 = cl4(wsf + OFF_H3Q + t4);
            f32x4 d4s = {0.f, 0.f, 0.f, 0.f};
            if (tid < 192) d4s = cl4(wsf + OFF_D4Q + t4);
            float d1qj = clf(wsf + OFF_D1Q + jw);
            float d2qj = clf(wsf + OFF_D2Q + jw);
            float d3qj = clf(wsf + OFF_D3Q + jw);
            f32x4 xp0 = *(const f32x4*)(xpE + 12 * lane);
            f32x4 xp1 = *(const f32x4*)(xpE + 12 * lane + 4);
            f32x4 xp2 = *(const f32x4*)(xpE + 12 * lane + 8);
            vwait();
            {
                int st = swz(t4);
                *(f32x4*)(smem + ST0 + st) = a0;
                *(f32x4*)(smem + ST1 + st) = a1;
            }
            if (tid < 192) *(f32x4*)(smem + SD4Q + t4) = d4s;
            __syncthreads();
            updc(w1c0, xp0, d1qj); updc(w1c1, xp1, d1qj); updc(w1c2, xp2, d1qj);
#define EPW2C(i) { f32x4 hf = LDS_SW(ST0, i); f32x4 af; \
                   af.x = DEC * hf.x; af.y = DEC * hf.y; af.z = DEC * hf.z; af.w = DEC * hf.w; \
                   updc(w2c##i, af, d2qj); }
            L8M(EPW2C)
#undef EPW2C
#define EPW3C(i) { f32x4 hq = LDS_SW(ST1, i); updc(w3c##i, hq, d3qj); }
            L8M(EPW3C)
#undef EPW3C
            {
                float vq0 = smem[SD4Q + c3 + 0];
                float vq1 = smem[SD4Q + c3 + 1];
                float vq2 = smem[SD4Q + c3 + 2];
                updc(w4c0, hq3, vq0); updc(w4c1, hq3, vq1); updc(w4c2, hq3, vq2);
            }
            if (lane == 0) {
                b1g[jw] = DEC * b1g[jw] - LRC * d1qj;
                b2g[jw] = DEC * b2g[jw] - LRC * d2qj;
                b3g[jw] = DEC * b3g[jw] - LRC * d3qj;
            }
            if (tid < 3) b4g[c3 + tid] = DEC * b4g[c3 + tid] - LRC * smem[SD4Q + c3 + tid];
        }
    }

    // ===== write register weights back to global (transpose via LDS) =====
    __syncthreads();
    {   // W2
#define WBW2(i) { smem[(32 * lane + 4 * (i) + 0) * 8 + w] = w2c##i.x; \
                  smem[(32 * lane + 4 * (i) + 1) * 8 + w] = w2c##i.y; \
                  smem[(32 * lane + 4 * (i) + 2) * 8 + w] = w2c##i.z; \
                  smem[(32 * lane + 4 * (i) + 3) * 8 + w] = w2c##i.w; }
        L8M(WBW2)
#undef WBW2
        __syncthreads();
#pragma unroll
        for (int r2 = 0; r2 < 4; ++r2) {
            int r = t4 + r2;
            *(f32x4*)(W2g + (size_t)r * 2048 + 8 * b) = *(const f32x4*)(smem + r * 8);
            *(f32x4*)(W2g + (size_t)r * 2048 + 8 * b + 4) = *(const f32x4*)(smem + r * 8 + 4);
        }
        __syncthreads();
    }
    {   // W3
#define WBW3(i) { smem[(32 * lane + 4 * (i) + 0) * 8 + w] = w3c##i.x; \
                  smem[(32 * lane + 4 * (i) + 1) * 8 + w] = w3c##i.y; \
                  smem[(32 * lane + 4 * (i) + 2) * 8 + w] = w3c##i.z; \
                  smem[(32 * lane + 4 * (i) + 3) * 8 + w] = w3c##i.w; }
        L8M(WBW3)
#undef WBW3
        __syncthreads();
#pragma unroll
        for (int r2 = 0; r2 < 4; ++r2) {
            int r = t4 + r2;
            *(f32x4*)(W3g + (size_t)r * 2048 + 8 * b) = *(const f32x4*)(smem + r * 8);
            *(f32x4*)(W3g + (size_t)r * 2048 + 8 * b + 4) = *(const f32x4*)(smem + r * 8 + 4);
        }
        __syncthreads();
    }
    {   // W1
#define WBW1(i) { smem[(12 * lane + 4 * (i) + 0) * 8 + w] = w1c##i.x; \
                  smem[(12 * lane + 4 * (i) + 1) * 8 + w] = w1c##i.y; \
                  smem[(12 * lane + 4 * (i) + 2) * 8 + w] = w1c##i.z; \
                  smem[(12 * lane + 4 * (i) + 3) * 8 + w] = w1c##i.w; }
        L3M(WBW1)
#undef WBW1
        __syncthreads();
        for (int r = tid; r < 768; r += 512) {
            *(f32x4*)(W1g + (size_t)r * 2048 + 8 * b) = *(const f32x4*)(smem + r * 8);
            *(f32x4*)(W1g + (size_t)r * 2048 + 8 * b + 4) = *(const f32x4*)(smem + r * 8 + 4);
        }
        __syncthreads();
    }
    {   // W4
#define WBW4(c) { smem[(4 * tid + 0) * 3 + (c)] = w4c##c.x; \
                  smem[(4 * tid + 1) * 3 + (c)] = w4c##c.y; \
                  smem[(4 * tid + 2) * 3 + (c)] = w4c##c.z; \
                  smem[(4 * tid + 3) * 3 + (c)] = w4c##c.w; }
        L3M(WBW4)
#undef WBW4
        __syncthreads();
#pragma unroll
        for (int r2 = 0; r2 < 4; ++r2) {
            int r = t4 + r2;
            W4g[(size_t)r * 768 + c3 + 0] = smem[r * 3 + 0];
            W4g[(size_t)r * 768 + c3 + 1] = smem[r * 3 + 1];
            W4g[(size_t)r * 768 + c3 + 2] = smem[r * 3 + 2];
        }
    }
}

// ---------- final batch forward: fp32 tiled GEMM C = act(A@W + bias) ----------
__global__ __launch_bounds__(256) void k_gemm(const float* __restrict__ A,
                                              const float* __restrict__ W,
                                              const float* __restrict__ bias,
                                              float* __restrict__ C,
                                              int M, int N, int K, int do_relu) {
    __shared__ float sA[16][64];
    __shared__ float sB[16][128];
    int bn = blockIdx.x, bm = blockIdx.y;
    int m0 = bm * 64, n0 = bn * 128;
    int tid = threadIdx.x;
    int tx = tid & 31, ty = tid >> 5;
    float acc[8][4];
#pragma unroll
    for (int i = 0; i < 8; ++i)
#pragma unroll
        for (int j = 0; j < 4; ++j) acc[i][j] = 0.f;

    for (int kt = 0; kt < K; kt += 16) {
        {
            int r = tid >> 2, cc = (tid & 3) * 4;
            const float4 a4 = *(const float4*)(A + (size_t)(m0 + r) * K + kt + cc);
            sA[cc + 0][r] = a4.x; sA[cc + 1][r] = a4.y; sA[cc + 2][r] = a4.z; sA[cc + 3][r] = a4.w;
        }
        {
            int r = tid >> 5, cc = (tid & 31) * 4;
            *(float4*)(&sB[r][cc]) = *(const float4*)(W + (size_t)(kt + r) * N + n0 + cc);
            *(float4*)(&sB[r + 8][cc]) = *(const float4*)(W + (size_t)(kt + r + 8) * N + n0 + cc);
        }
        __syncthreads();
#pragma unroll
        for (int k = 0; k < 16; ++k) {
            float av[8];
#pragma unroll
            for (int i = 0; i < 8; ++i) av[i] = sA[k][ty * 8 + i];
            float bx = sB[k][tx * 4 + 0], by = sB[k][tx * 4 + 1];
            float bz = sB[k][tx * 4 + 2], bw = sB[k][tx * 4 + 3];
#pragma unroll
            for (int i = 0; i < 8; ++i) {
                acc[i][0] += av[i] * bx; acc[i][1] += av[i] * by;
                acc[i][2] += av[i] * bz; acc[i][3] += av[i] * bw;
            }
        }
        __syncthreads();
    }
    float bx = bias[n0 + tx * 4 + 0], by = bias[n0 + tx * 4 + 1];
    float bz = bias[n0 + tx * 4 + 2], bw = bias[n0 + tx * 4 + 3];
#pragma unroll
    for (int i = 0; i < 8; ++i) {
        int m = m0 + ty * 8 + i;
        float4 v;
        v.x = acc[i][0] + bx; v.y = acc[i][1] + by;
        v.z = acc[i][2] + bz; v.w = acc[i][3] + bw;
        if (do_relu) {
            v.x = fmaxf(v.x, 0.f); v.y = fmaxf(v.y, 0.f);
            v.z = fmaxf(v.z, 0.f); v.w = fmaxf(v.w, 0.f);
        }
        *(float4*)(C + (size_t)m * N + n0 + tx * 4) = v;
    }
}

__global__ __launch_bounds__(128) void k_colsum(const float* __restrict__ Y,
                                                float* __restrict__ out) {
    int c = blockIdx.x * 128 + threadIdx.x;
    int r0 = blockIdx.y * 128;
    float s = 0.f;
    for (int r = 0; r < 128; ++r) s += Y[(size_t)(r0 + r) * 768 + c];
    out[blockIdx.y * 768 + c] = s;
}

__global__ __launch_bounds__(768) void k_out(const float* __restrict__ msum,
                                             float* __restrict__ out) {
    int c = threadIdx.x;
    float s = 0.f;
#pragma unroll
    for (int i = 0; i < 32; ++i) s += msum[i * 768 + c];
    out[c] = s * (1.f / 4096.f);
}

extern "C" void kernel_launch(void* const* d_in, const int* in_sizes, int n_in,
                              void* d_out, int out_size, void* d_ws, size_t ws_size,
                              hipStream_t stream) {
    const float* x = (const float*)d_in[0];
    float* W1 = (float*)d_in[1];
    float* b1 = (float*)d_in[2];
    float* W2 = (float*)d_in[3];
    float* b2 = (float*)d_in[4];
    float* W3 = (float*)d_in[5];
    float* b3 = (float*)d_in[6];
    float* W4 = (float*)d_in[7];
    float* b4 = (float*)d_in[8];
    const int* flag = (const int*)d_in[9];
    float* wsf = (float*)d_ws;

    unsigned* bar = (unsigned*)(wsf + OFF_HA);
    k_zero<<<1, 1024, 0, stream>>>(bar);

    // entire 1024-step TTT scan: ONE persistent kernel, register weights + XCD staging
    k_scan<<<256, 512, 0, stream>>>(x, W1, b1, W2, b2, W3, b3, W4, b4, wsf, flag);

    // final forward over all 4096 tokens, chunked by 1024, + mean
    float* HA = wsf + OFF_HA;
    float* HB = wsf + OFF_HB;
    for (int ch = 0; ch < 4; ++ch) {
        const float* Xc = x + (size_t)ch * 1024 * 768;
        k_gemm<<<dim3(16, 16), 256, 0, stream>>>(Xc, W1, b1, HA, 1024, 2048, 768, 1);
        k_gemm<<<dim3(16, 16), 256, 0, stream>>>(HA, W2, b2, HB, 1024, 2048, 2048, 1);
        k_gemm<<<dim3(16, 16), 256, 0, stream>>>(HB, W3, b3, HA, 1024, 2048, 2048, 1);
        k_gemm<<<dim3(6, 16), 256, 0, stream>>>(HA, W4, b4, HB, 1024, 768, 2048, 0);
        k_colsum<<<dim3(6, 8), 128, 0, stream>>>(HB, wsf + OFF_MSUM + (size_t)ch * 8 * 768);
    }
    k_out<<<1, 768, 0, stream>>>(wsf + OFF_MSUM, (float*)d_out);
}

// Round 9
// 60261.902 us; speedup vs baseline: 1.7704x; 1.7704x over previous
//
#include <hip/hip_runtime.h>
#include <cstddef>

#define LRC 0.001f
#define DEC 0.99f

typedef float f32x4 __attribute__((ext_vector_type(4)));

// ---------------- workspace layout (float offsets) ----------------
static const size_t OFF_H1F = 376832;       // 2048
static const size_t OFF_H2F = 380928;
static const size_t OFF_H2Q = 382976;
static const size_t OFF_H3F = 385024;
static const size_t OFF_H3Q = 387072;
static const size_t OFF_D4F = 389120;       // 768
static const size_t OFF_D4Q = 389888;       // 768
static const size_t OFF_D3F = 390656;       // 2048
static const size_t OFF_D3Q = 392704;
static const size_t OFF_D2F = 394752;
static const size_t OFF_D2Q = 396800;
static const size_t OFF_SL4 = 398848;       // 256
static const size_t OFF_D1Q = 400896;       // 2048
static const size_t OFF_NSQ = 402944;       // 16
static const size_t OFF_SL3 = 402960;       // 256
static const size_t OFF_SL2 = 403216;
static const size_t OFF_SL1 = 403472;       // ends 403728
static const size_t OFF_MSUM = 403732;      // [32][768]
static const size_t OFF_HA  = 428308;       // barrier state during scan
static const size_t OFF_HB  = 2525460;      // GEMM scratch

// ---------------- LDS map (float indices) ----------------
// Persistent per-step caches (survive into next step's phase A):
#define PH1F 0
#define PH2F 2048
#define PH2Q 4096
#define PH3Q 6144
#define PD2Q 8192
#define PD3Q 10240
#define PD4Q 12288
#define SD4F 13056
#define ST0  13824
#define ST2  15872
#define SRED 17920
#define SCND 18432
#define SBUF 18436
#define SCOND 18437
#define SB4  18440
#define SSQ  18448
#define SWRP 18456
#define SWRQ 18480
#define PD1W 18504

// ---------------- coherent (L3) access helpers ----------------
__device__ __forceinline__ float clf(const float* p) {
    return __hip_atomic_load(p, __ATOMIC_RELAXED, __HIP_MEMORY_SCOPE_AGENT);
}
__device__ __forceinline__ void csf(float* p, float v) {
    __hip_atomic_store(p, v, __ATOMIC_RELAXED, __HIP_MEMORY_SCOPE_AGENT);
}
__device__ __forceinline__ f32x4 cl4(const float* p) {
    f32x4 r;
    asm volatile("global_load_dwordx4 %0, %1, off sc0 sc1" : "=&v"(r) : "v"(p) : "memory");
    return r;
}
__device__ __forceinline__ void vwait() {
    asm volatile("s_waitcnt vmcnt(0)" ::: "memory");
    __builtin_amdgcn_sched_barrier(0);   // rule #18: pin uses after the waitcnt
}

__device__ __forceinline__ float dot4(const f32x4 a, const f32x4 b) {
    float s = a.x * b.x; s += a.y * b.y; s += a.z * b.z; s += a.w * b.w; return s;
}
__device__ __forceinline__ int swz(int p) { return p ^ (((p >> 5) & 7) << 2); }

__device__ __forceinline__ void updc(f32x4& wv, const f32x4 a, float dq) {
    wv.x = DEC * wv.x - (LRC * a.x) * dq;
    wv.y = DEC * wv.y - (LRC * a.y) * dq;
    wv.z = DEC * wv.z - (LRC * a.z) * dq;
    wv.w = DEC * wv.w - (LRC * a.w) * dq;
}
__device__ __forceinline__ void updr(f32x4& wv, float u, const f32x4 dv) {
    wv.x = DEC * wv.x - u * dv.x;
    wv.y = DEC * wv.y - u * dv.y;
    wv.z = DEC * wv.z - u * dv.z;
    wv.w = DEC * wv.w - u * dv.w;
}

__device__ __forceinline__ float block_reduce_512s(float v, float* red) {
    int t = threadIdx.x;
    red[t] = v;
    __syncthreads();
    for (int st = 256; st > 0; st >>= 1) {
        if (t < st) red[t] += red[t + st];
        __syncthreads();
    }
    float r = red[0];
    __syncthreads();
    return r;
}

// ---- global grid barrier, fence-free (proven rounds 5/7/8) ----
__device__ __forceinline__ void gbar(unsigned* bar) {
    asm volatile("s_waitcnt vmcnt(0) lgkmcnt(0)" ::: "memory");
    __syncthreads();
    if (threadIdx.x == 0) {
        unsigned g = __hip_atomic_load(bar, __ATOMIC_RELAXED, __HIP_MEMORY_SCOPE_AGENT);
        asm volatile("s_waitcnt vmcnt(0)" ::: "memory");
        unsigned* grp = bar + 64 + ((blockIdx.x >> 4) << 5);
        bool released = false;
        if (__hip_atomic_fetch_add(grp, 1u, __ATOMIC_RELAXED, __HIP_MEMORY_SCOPE_AGENT) == 15u) {
            if (__hip_atomic_fetch_add(bar + 32, 1u, __ATOMIC_RELAXED, __HIP_MEMORY_SCOPE_AGENT) == 15u) {
#pragma unroll
                for (int i = 0; i < 16; ++i)
                    __hip_atomic_store(bar + 64 + (i << 5), 0u, __ATOMIC_RELAXED, __HIP_MEMORY_SCOPE_AGENT);
                __hip_atomic_store(bar + 32, 0u, __ATOMIC_RELAXED, __HIP_MEMORY_SCOPE_AGENT);
                __hip_atomic_store(bar, g + 1u, __ATOMIC_RELEASE, __HIP_MEMORY_SCOPE_AGENT);
                released = true;
            }
        }
        if (!released) {
            while (__hip_atomic_load(bar, __ATOMIC_RELAXED, __HIP_MEMORY_SCOPE_AGENT) == g)
                __builtin_amdgcn_s_sleep(2);
            (void)__hip_atomic_load(bar, __ATOMIC_ACQUIRE, __HIP_MEMORY_SCOPE_AGENT);
        }
    }
    __syncthreads();
}

__global__ __launch_bounds__(1024) void k_zero(unsigned* __restrict__ bar) {
    bar[threadIdx.x] = 0u;
}

#define L3M(M) M(0) M(1) M(2)
#define L8M(M) M(0) M(1) M(2) M(3) M(4) M(5) M(6) M(7)
#define LDS_SW(buf, i) (*(const f32x4*)(smem + (buf) + swz(32 * lane + 4 * (i))))
#define LDS_D4(buf, i) (*(const f32x4*)(smem + (buf) + 12 * lane + 4 * (i)))

// ---------- the entire TTT scan: register weights + persistent-LDS broadcast cache ----------
__global__ __attribute__((amdgpu_flat_work_group_size(512, 512), amdgpu_waves_per_eu(2, 2)))
void k_scan(const float* __restrict__ x,
            float* __restrict__ W1g, float* __restrict__ b1g,
            float* __restrict__ W2g, float* __restrict__ b2g,
            float* __restrict__ W3g, float* __restrict__ b3g,
            float* __restrict__ W4g, float* __restrict__ b4g,
            float* __restrict__ wsf,
            const int* __restrict__ flag) {
    if (*flag == 0) return;
    __shared__ __align__(16) float smem[18512];
    unsigned* bar = (unsigned*)(wsf + OFF_HA);
    const int b = blockIdx.x, tid = threadIdx.x;
    const int w = tid >> 6, lane = tid & 63;
    const int jw = 8 * b + w;
    const int c3 = 3 * b;
    const int t4 = tid * 4;

    // ---- named register shards ----
    f32x4 w1c0, w1c1, w1c2;
    f32x4 w2c0, w2c1, w2c2, w2c3, w2c4, w2c5, w2c6, w2c7;
    f32x4 w3c0, w3c1, w3c2, w3c3, w3c4, w3c5, w3c6, w3c7;
    f32x4 w4c0, w4c1, w4c2;
    f32x4 w4r0, w4r1, w4r2;
    f32x4 w2r0, w2r1, w2r2, w2r3, w2r4, w2r5, w2r6, w2r7;
    f32x4 w3r0, w3r1, w3r2, w3r3, w3r4, w3r5, w3r6, w3r7;

#define LD_COL(dst, Wg, ld, row0, col) { f32x4 t; \
    t.x = Wg[(size_t)((row0) + 0) * (ld) + (col)]; \
    t.y = Wg[(size_t)((row0) + 1) * (ld) + (col)]; \
    t.z = Wg[(size_t)((row0) + 2) * (ld) + (col)]; \
    t.w = Wg[(size_t)((row0) + 3) * (ld) + (col)]; dst = t; }
#define LDW1C(i) LD_COL(w1c##i, W1g, 2048, 12 * lane + 4 * (i), jw)
    L3M(LDW1C)
#undef LDW1C
#define LDW2C(i) LD_COL(w2c##i, W2g, 2048, 32 * lane + 4 * (i), jw)
    L8M(LDW2C)
#undef LDW2C
#define LDW3C(i) LD_COL(w3c##i, W3g, 2048, 32 * lane + 4 * (i), jw)
    L8M(LDW3C)
#undef LDW3C
#define LDW4C(i) LD_COL(w4c##i, W4g, 768, 4 * tid, c3 + (i))
    L3M(LDW4C)
#undef LDW4C
#define LDW4R(i) w4r##i = *(const f32x4*)(W4g + (size_t)jw * 768 + 12 * lane + 4 * (i));
    L3M(LDW4R)
#undef LDW4R
#define LDW2R(i) w2r##i = *(const f32x4*)(W2g + (size_t)jw * 2048 + 32 * lane + 4 * (i));
    L8M(LDW2R)
#undef LDW2R
#define LDW3R(i) w3r##i = *(const f32x4*)(W3g + (size_t)jw * 2048 + 32 * lane + 4 * (i));
    L8M(LDW3R)
#undef LDW3R
    if (tid == 0) smem[SBUF] = 0.f;

    for (int s = 0; s < 1024; ++s) {
        const float* xt = x + (size_t)s * 3072;
        const float* xprev = x + (size_t)(s > 0 ? s - 1 : 0) * 3072;

        // ===== Phase A: cond + apply step-(s-1) update (all operands from persistent LDS) =====
        float cond = 0.f;
        if (s > 0) {
            if (w < 4) {
                const float* sl = wsf + (w == 0 ? OFF_SL1 : w == 1 ? OFF_SL2 : w == 2 ? OFF_SL3 : OFF_SL4);
                float v = clf(sl + lane) + clf(sl + lane + 64) + clf(sl + lane + 128) + clf(sl + lane + 192);
#pragma unroll
                for (int off = 32; off > 0; off >>= 1) v += __shfl_down(v, off);
                if (lane == 0) smem[SCND + w] = v;
            }
            __syncthreads();
            if (tid == 0) {
                float nd1 = sqrtf(smem[SCND + 0]), nd2 = sqrtf(smem[SCND + 1]);
                float nd3 = sqrtf(smem[SCND + 2]), nd4 = sqrtf(smem[SCND + 3]);
                float nx = sqrtf(clf(wsf + OFF_NSQ + 0));
                float nh1 = sqrtf(clf(wsf + OFF_NSQ + 1));
                float nh2 = sqrtf(clf(wsf + OFF_NSQ + 2));
                float nh3 = sqrtf(clf(wsf + OFF_NSQ + 3));
                float surprise = nx * nd1 + nd1 + nh1 * nd2 + nd2 + nh2 * nd3 + nd3 + nh3 * nd4 + nd4;
                float bufold = smem[SBUF];
                float bufnew = (s == 1) ? surprise : (0.9f * bufold + 0.1f * surprise);
                smem[SBUF] = bufnew;
                smem[SCOND] = (bufnew > 0.1f) ? 1.f : 0.f;
            }
            __syncthreads();
            cond = smem[SCOND];
        }
        float b1j;
        if (cond != 0.f) {
            float ob1 = b1g[jw];
            f32x4 xp0 = *(const f32x4*)(xprev + 12 * lane);
            f32x4 xp1 = *(const f32x4*)(xprev + 12 * lane + 4);
            f32x4 xp2 = *(const f32x4*)(xprev + 12 * lane + 8);
            float d1qj = smem[PD1W + w];
            // W1 col-shard (u = LRC*xprev[k])
            updc(w1c0, xp0, d1qj); updc(w1c1, xp1, d1qj); updc(w1c2, xp2, d1qj);
            // W2 col-shard (u = LRC*(DEC*h1f[k]))
            {
                float d2qj = smem[PD2Q + swz(jw)];
#define UPW2C(i) { f32x4 hf = LDS_SW(PH1F, i); f32x4 af; \
                   af.x = DEC * hf.x; af.y = DEC * hf.y; af.z = DEC * hf.z; af.w = DEC * hf.w; \
                   updc(w2c##i, af, d2qj); }
                L8M(UPW2C)
#undef UPW2C
            }
            // W3 col-shard (u = LRC*h2q[k])
            {
                float d3qj = smem[PD3Q + swz(jw)];
#define UPW3C(i) { f32x4 hq = LDS_SW(PH2Q, i); updc(w3c##i, hq, d3qj); }
                L8M(UPW3C)
#undef UPW3C
            }
            // W4 col-shard (u = LRC*h3q[k])
            {
                f32x4 hq3 = *(const f32x4*)(smem + PH3Q + swz(t4));
                float vq0 = smem[PD4Q + c3 + 0];
                float vq1 = smem[PD4Q + c3 + 1];
                float vq2 = smem[PD4Q + c3 + 2];
                updc(w4c0, hq3, vq0); updc(w4c1, hq3, vq1); updc(w4c2, hq3, vq2);
            }
            // W4 row-shard
            {
                float u = LRC * smem[PH3Q + swz(jw)];
#define UPW4R(i) { f32x4 dv = LDS_D4(PD4Q, i); updr(w4r##i, u, dv); }
                L3M(UPW4R)
#undef UPW4R
            }
            // W3 row-shard
            {
                float u = LRC * smem[PH2Q + swz(jw)];
#define UPW3R(i) { f32x4 dv = LDS_SW(PD3Q, i); updr(w3r##i, u, dv); }
                L8M(UPW3R)
#undef UPW3R
            }
            // W2 row-shard
            {
                float u = LRC * (DEC * smem[PH1F + swz(jw)]);
#define UPW2R(i) { f32x4 dv = LDS_SW(PD2Q, i); updr(w2r##i, u, dv); }
                L8M(UPW2R)
#undef UPW2R
            }
            b1j = DEC * ob1 - LRC * d1qj;
            if (lane == 0) b1g[jw] = b1j;
        } else {
            b1j = b1g[jw];
        }
        {   // layer-1 forward: h1[jw]
            f32x4 x0 = *(const f32x4*)(xt + 12 * lane);
            f32x4 x1 = *(const f32x4*)(xt + 12 * lane + 4);
            f32x4 x2 = *(const f32x4*)(xt + 12 * lane + 8);
            float acc = dot4(w1c0, x0);
            acc += dot4(w1c1, x1);
            acc += dot4(w1c2, x2);
#pragma unroll
            for (int off = 32; off > 0; off >>= 1) acc += __shfl_down(acc, off);
            if (lane == 0) csf(wsf + OFF_H1F + jw, fmaxf(acc + b1j, 0.f));
        }
        gbar(bar);

        // ===== Phase B: layer 2 (caches H1F -> PH1F) =====
        {
            f32x4 hv = cl4(wsf + OFF_H1F + t4);
            float ob2 = b2g[jw];
            float d2qjo = (cond != 0.f) ? smem[PD2Q + swz(jw)] : 0.f;
            vwait();
            *(f32x4*)(smem + PH1F + swz(t4)) = hv;
            float b2j = (cond != 0.f) ? (DEC * ob2 - LRC * d2qjo) : ob2;
            if (cond != 0.f && lane == 0) b2g[jw] = b2j;
            __syncthreads();
            float accP = 0.f, accQ = 0.f;
#define PHB(i) { const f32x4 hf = LDS_SW(PH1F, i); f32x4 hq; \
                 hq.x = DEC * hf.x; hq.y = DEC * hf.y; hq.z = DEC * hf.z; hq.w = DEC * hf.w; \
                 accP += dot4(w2c##i, hf); accQ += dot4(w2c##i, hq); }
            L8M(PHB)
#undef PHB
#pragma unroll
            for (int off = 32; off > 0; off >>= 1) {
                accP += __shfl_down(accP, off);
                accQ += __shfl_down(accQ, off);
            }
            if (lane == 0) {
                csf(wsf + OFF_H2F + jw, fmaxf(accP + b2j, 0.f));
                csf(wsf + OFF_H2Q + jw, fmaxf(DEC * (accQ + b2j), 0.f));
            }
        }
        gbar(bar);

        // ===== Phase C: layer 3 (caches H2F/H2Q -> PH2F/PH2Q) =====
        {
            f32x4 hfv = cl4(wsf + OFF_H2F + t4);
            f32x4 hqv = cl4(wsf + OFF_H2Q + t4);
            float ob3 = b3g[jw];
            float d3qjo = (cond != 0.f) ? smem[PD3Q + swz(jw)] : 0.f;
            vwait();
            {
                int st = swz(t4);
                *(f32x4*)(smem + PH2F + st) = hfv;
                *(f32x4*)(smem + PH2Q + st) = hqv;
            }
            float b3j = (cond != 0.f) ? (DEC * ob3 - LRC * d3qjo) : ob3;
            if (cond != 0.f && lane == 0) b3g[jw] = b3j;
            __syncthreads();
            float accP = 0.f, accQ = 0.f;
#define PHC(i) { const f32x4 hf = LDS_SW(PH2F, i); const f32x4 hq = LDS_SW(PH2Q, i); \
                 accP += dot4(w3c##i, hf); accQ += dot4(w3c##i, hq); }
            L8M(PHC)
#undef PHC
#pragma unroll
            for (int off = 32; off > 0; off >>= 1) {
                accP += __shfl_down(accP, off);
                accQ += __shfl_down(accQ, off);
            }
            if (lane == 0) {
                csf(wsf + OFF_H3F + jw, fmaxf(accP + b3j, 0.f));
                csf(wsf + OFF_H3Q + jw, fmaxf(DEC * (accQ + b3j), 0.f));
            }
        }
        gbar(bar);

        // ===== Phase D: layer 4 + d4 + slots/norms (caches H3Q -> PH3Q, H3F -> ST0) =====
        {
            f32x4 hfv = cl4(wsf + OFF_H3F + t4);
            f32x4 hqv = cl4(wsf + OFF_H3Q + t4);
            float tv = 0.f;
            if (tid < 3) {
                float ob4 = b4g[c3 + tid];
                float d4qjo = (cond != 0.f) ? smem[PD4Q + c3 + tid] : 0.f;
                tv = xt[c3 + tid];
                float bn = (cond != 0.f) ? (DEC * ob4 - LRC * d4qjo) : ob4;
                if (cond != 0.f) b4g[c3 + tid] = bn;
                smem[SB4 + tid] = bn;
            }
            vwait();
            {
                int st = swz(t4);
                *(f32x4*)(smem + ST0 + st) = hfv;    // E's f-gate
                *(f32x4*)(smem + PH3Q + st) = hqv;   // E's q-gate + next-A
            }
            float aP0 = dot4(w4c0, hfv), aP1 = dot4(w4c1, hfv), aP2 = dot4(w4c2, hfv);
            float aQ0 = dot4(w4c0, hqv), aQ1 = dot4(w4c1, hqv), aQ2 = dot4(w4c2, hqv);
#pragma unroll
            for (int off = 32; off > 0; off >>= 1) {
                aP0 += __shfl_down(aP0, off); aP1 += __shfl_down(aP1, off); aP2 += __shfl_down(aP2, off);
                aQ0 += __shfl_down(aQ0, off); aQ1 += __shfl_down(aQ1, off); aQ2 += __shfl_down(aQ2, off);
            }
            if (lane == 0) {
                smem[SWRP + w * 3 + 0] = aP0; smem[SWRP + w * 3 + 1] = aP1; smem[SWRP + w * 3 + 2] = aP2;
                smem[SWRQ + w * 3 + 0] = aQ0; smem[SWRQ + w * 3 + 1] = aQ1; smem[SWRQ + w * 3 + 2] = aQ2;
            }
            __syncthreads();
            if (tid < 3) {
                float zp = 0.f, zq = 0.f;
#pragma unroll
                for (int q = 0; q < 8; ++q) { zp += smem[SWRP + q * 3 + tid]; zq += smem[SWRQ + q * 3 + tid]; }
                float bn = smem[SB4 + tid];
                float d4f = 2.f * ((zp + bn) - tv) * (1.f / 768.f);
                float d4q = 2.f * (DEC * (zq + bn) - tv) * (1.f / 768.f);
                csf(wsf + OFF_D4F + c3 + tid, d4f);
                csf(wsf + OFF_D4Q + c3 + tid, d4q);
                smem[SSQ + tid] = d4f * d4f;
            }
            __syncthreads();
            if (tid == 0) csf(wsf + OFF_SL4 + b, smem[SSQ + 0] + smem[SSQ + 1] + smem[SSQ + 2]);
            if (b >= 1 && b <= 4) {
                float v = 0.f;
                if (b == 4) {
                    if (tid < 192) {
                        f32x4 xv = *(const f32x4*)(xt + t4);
                        v = xv.x * xv.x + xv.y * xv.y + xv.z * xv.z + xv.w * xv.w;
                    }
                } else {
                    const int so = (b == 1) ? PH1F : (b == 2) ? PH2F : ST0;
                    f32x4 hh = *(const f32x4*)(smem + so + swz(t4));
                    v = hh.x * hh.x + hh.y * hh.y + hh.z * hh.z + hh.w * hh.w;
                }
                float sres = block_reduce_512s(v, smem + SRED);
                if (tid == 0) csf(wsf + OFF_NSQ + ((b == 4) ? 0 : b), sres);
            }
        }
        gbar(bar);

        // ===== Phase E: W4^T backward -> d3 (caches D4Q -> PD4Q) =====
        {
            f32x4 p4 = {0.f, 0.f, 0.f, 0.f}, q4 = {0.f, 0.f, 0.f, 0.f};
            if (tid < 192) {
                p4 = cl4(wsf + OFF_D4F + t4);
                q4 = cl4(wsf + OFF_D4Q + t4);
            }
            vwait();
            if (tid < 192) {
                *(f32x4*)(smem + SD4F + t4) = p4;
                *(f32x4*)(smem + PD4Q + t4) = q4;
            }
            __syncthreads();
            float accP = 0.f, accQ = 0.f;
#define PHE(i) { const f32x4 dP = LDS_D4(SD4F, i); const f32x4 dQ = LDS_D4(PD4Q, i); \
                 accP += dot4(w4r##i, dP); accQ += dot4(w4r##i, dQ); }
            L3M(PHE)
#undef PHE
#pragma unroll
            for (int off = 32; off > 0; off >>= 1) {
                accP += __shfl_down(accP, off);
                accQ += __shfl_down(accQ, off);
            }
            if (lane == 0) {
                float dp = (smem[ST0 + swz(jw)] > 0.f) ? accP : 0.f;
                float dq = (smem[PH3Q + swz(jw)] > 0.f) ? DEC * accQ : 0.f;
                csf(wsf + OFF_D3F + jw, dp);
                csf(wsf + OFF_D3Q + jw, dq);
                smem[SSQ + w] = dp * dp;
            }
            __syncthreads();
            if (tid == 0) {
                float ss = 0.f;
#pragma unroll
                for (int q = 0; q < 8; ++q) ss += smem[SSQ + q];
                csf(wsf + OFF_SL3 + b, ss);
            }
        }
        gbar(bar);

        // ===== Phase F: W3^T backward -> d2 (caches D3Q -> PD3Q) =====
        {
            f32x4 fP = cl4(wsf + OFF_D3F + t4);
            f32x4 fQ = cl4(wsf + OFF_D3Q + t4);
            float h2fr = smem[PH2F + swz(jw)];
            float h2qr = smem[PH2Q + swz(jw)];
            vwait();
            {
                int st = swz(t4);
                *(f32x4*)(smem + ST2 + st) = fP;
                *(f32x4*)(smem + PD3Q + st) = fQ;
            }
            __syncthreads();
            float accP = 0.f, accQ = 0.f;
#define PHF(i) { const f32x4 dP = LDS_SW(ST2, i); const f32x4 dQ = LDS_SW(PD3Q, i); \
                 accP += dot4(w3r##i, dP); accQ += dot4(w3r##i, dQ); }
            L8M(PHF)
#undef PHF
#pragma unroll
            for (int off = 32; off > 0; off >>= 1) {
                accP += __shfl_down(accP, off);
                accQ += __shfl_down(accQ, off);
            }
            if (lane == 0) {
                float dp = (h2fr > 0.f) ? accP : 0.f;
                float dq = (h2qr > 0.f) ? DEC * accQ : 0.f;
                csf(wsf + OFF_D2F + jw, dp);
                csf(wsf + OFF_D2Q + jw, dq);
                smem[SSQ + w] = dp * dp;
            }
            __syncthreads();
            if (tid == 0) {
                float ss = 0.f;
#pragma unroll
                for (int q = 0; q < 8; ++q) ss += smem[SSQ + q];
                csf(wsf + OFF_SL2 + b, ss);
            }
        }
        gbar(bar);

        // ===== Phase G: W2^T backward -> d1 (caches D2Q -> PD2Q, own d1q -> PD1W) =====
        {
            f32x4 fP = cl4(wsf + OFF_D2F + t4);
            f32x4 fQ = cl4(wsf + OFF_D2Q + t4);
            float h1fr = smem[PH1F + swz(jw)];
            vwait();
            {
                int st = swz(t4);
                *(f32x4*)(smem + ST0 + st) = fP;
                *(f32x4*)(smem + PD2Q + st) = fQ;
            }
            __syncthreads();
            float accP = 0.f, accQ = 0.f;
#define PHG(i) { const f32x4 dP = LDS_SW(ST0, i); const f32x4 dQ = LDS_SW(PD2Q, i); \
                 accP += dot4(w2r##i, dP); accQ += dot4(w2r##i, dQ); }
            L8M(PHG)
#undef PHG
#pragma unroll
            for (int off = 32; off > 0; off >>= 1) {
                accP += __shfl_down(accP, off);
                accQ += __shfl_down(accQ, off);
            }
            if (lane == 0) {
                float dp = (h1fr > 0.f) ? accP : 0.f;
                float h1qr = DEC * h1fr;
                float dq = (h1qr > 0.f) ? DEC * accQ : 0.f;
                csf(wsf + OFF_D1Q + jw, dq);
                smem[PD1W + w] = dq;
                smem[SSQ + w] = dp * dp;
            }
            __syncthreads();
            if (tid == 0) {
                float ss = 0.f;
#pragma unroll
                for (int q = 0; q < 8; ++q) ss += smem[SSQ + q];
                csf(wsf + OFF_SL1 + b, ss);
            }
        }
        gbar(bar);
    }

    // ===== Epilogue: apply final (step 1023) update from persistent LDS =====
    {
        if (w < 4) {
            const float* sl = wsf + (w == 0 ? OFF_SL1 : w == 1 ? OFF_SL2 : w == 2 ? OFF_SL3 : OFF_SL4);
            float v = clf(sl + lane) + clf(sl + lane + 64) + clf(sl + lane + 128) + clf(sl + lane + 192);
#pragma unroll
            for (int off = 32; off > 0; off >>= 1) v += __shfl_down(v, off);
            if (lane == 0) smem[SCND + w] = v;
        }
        __syncthreads();
        if (tid == 0) {
            float nd1 = sqrtf(smem[SCND + 0]), nd2 = sqrtf(smem[SCND + 1]);
            float nd3 = sqrtf(smem[SCND + 2]), nd4 = sqrtf(smem[SCND + 3]);
            float nx = sqrtf(clf(wsf + OFF_NSQ + 0));
            float nh1 = sqrtf(clf(wsf + OFF_NSQ + 1));
            float nh2 = sqrtf(clf(wsf + OFF_NSQ + 2));
            float nh3 = sqrtf(clf(wsf + OFF_NSQ + 3));
            float surprise = nx * nd1 + nd1 + nh1 * nd2 + nd2 + nh2 * nd3 + nd3 + nh3 * nd4 + nd4;
            float bufnew = 0.9f * smem[SBUF] + 0.1f * surprise;
            smem[SCOND] = (bufnew > 0.1f) ? 1.f : 0.f;
        }
        __syncthreads();
        if (smem[SCOND] != 0.f) {
            const float* xpE = x + (size_t)1023 * 3072;
            f32x4 xp0 = *(const f32x4*)(xpE + 12 * lane);
            f32x4 xp1 = *(const f32x4*)(xpE + 12 * lane + 4);
            f32x4 xp2 = *(const f32x4*)(xpE + 12 * lane + 8);
            float d1qj = smem[PD1W + w];
            updc(w1c0, xp0, d1qj); updc(w1c1, xp1, d1qj); updc(w1c2, xp2, d1qj);
            float d2qj = smem[PD2Q + swz(jw)];
            float d3qj = smem[PD3Q + swz(jw)];
#define EPW2C(i) { f32x4 hf = LDS_SW(PH1F, i); f32x4 af; \
                   af.x = DEC * hf.x; af.y = DEC * hf.y; af.z = DEC * hf.z; af.w = DEC * hf.w; \
                   updc(w2c##i, af, d2qj); }
            L8M(EPW2C)
#undef EPW2C
#define EPW3C(i) { f32x4 hq = LDS_SW(PH2Q, i); updc(w3c##i, hq, d3qj); }
            L8M(EPW3C)
#undef EPW3C
            {
                f32x4 hq3 = *(const f32x4*)(smem + PH3Q + swz(t4));
                float vq0 = smem[PD4Q + c3 + 0];
                float vq1 = smem[PD4Q + c3 + 1];
                float vq2 = smem[PD4Q + c3 + 2];
                updc(w4c0, hq3, vq0); updc(w4c1, hq3, vq1); updc(w4c2, hq3, vq2);
            }
            if (lane == 0) {
                b1g[jw] = DEC * b1g[jw] - LRC * d1qj;
                b2g[jw] = DEC * b2g[jw] - LRC * d2qj;
                b3g[jw] = DEC * b3g[jw] - LRC * d3qj;
            }
            if (tid < 3) b4g[c3 + tid] = DEC * b4g[c3 + tid] - LRC * smem[PD4Q + c3 + tid];
        }
    }

    // ===== write register weights back to global (transpose via LDS, reuse smem[0..]) =====
    __syncthreads();
    {   // W2
#define WBW2(i) { smem[(32 * lane + 4 * (i) + 0) * 8 + w] = w2c##i.x; \
                  smem[(32 * lane + 4 * (i) + 1) * 8 + w] = w2c##i.y; \
                  smem[(32 * lane + 4 * (i) + 2) * 8 + w] = w2c##i.z; \
                  smem[(32 * lane + 4 * (i) + 3) * 8 + w] = w2c##i.w; }
        L8M(WBW2)
#undef WBW2
        __syncthreads();
#pragma unroll
        for (int r2 = 0; r2 < 4; ++r2) {
            int r = t4 + r2;
            *(f32x4*)(W2g + (size_t)r * 2048 + 8 * b) = *(const f32x4*)(smem + r * 8);
            *(f32x4*)(W2g + (size_t)r * 2048 + 8 * b + 4) = *(const f32x4*)(smem + r * 8 + 4);
        }
        __syncthreads();
    }
    {   // W3
#define WBW3(i) { smem[(32 * lane + 4 * (i) + 0) * 8 + w] = w3c##i.x; \
                  smem[(32 * lane + 4 * (i) + 1) * 8 + w] = w3c##i.y; \
                  smem[(32 * lane + 4 * (i) + 2) * 8 + w] = w3c##i.z; \
                  smem[(32 * lane + 4 * (i) + 3) * 8 + w] = w3c##i.w; }
        L8M(WBW3)
#undef WBW3
        __syncthreads();
#pragma unroll
        for (int r2 = 0; r2 < 4; ++r2) {
            int r = t4 + r2;
            *(f32x4*)(W3g + (size_t)r * 2048 + 8 * b) = *(const f32x4*)(smem + r * 8);
            *(f32x4*)(W3g + (size_t)r * 2048 + 8 * b + 4) = *(const f32x4*)(smem + r * 8 + 4);
        }
        __syncthreads();
    }
    {   // W1
#define WBW1(i) { smem[(12 * lane + 4 * (i) + 0) * 8 + w] = w1c##i.x; \
                  smem[(12 * lane + 4 * (i) + 1) * 8 + w] = w1c##i.y; \
                  smem[(12 * lane + 4 * (i) + 2) * 8 + w] = w1c##i.z; \
                  smem[(12 * lane + 4 * (i) + 3) * 8 + w] = w1c##i.w; }
        L3M(WBW1)
#undef WBW1
        __syncthreads();
        for (int r = tid; r < 768; r += 512) {
            *(f32x4*)(W1g + (size_t)r * 2048 + 8 * b) = *(const f32x4*)(smem + r * 8);
            *(f32x4*)(W1g + (size_t)r * 2048 + 8 * b + 4) = *(const f32x4*)(smem + r * 8 + 4);
        }
        __syncthreads();
    }
    {   // W4
#define WBW4(c) { smem[(4 * tid + 0) * 3 + (c)] = w4c##c.x; \
                  smem[(4 * tid + 1) * 3 + (c)] = w4c##c.y; \
                  smem[(4 * tid + 2) * 3 + (c)] = w4c##c.z; \
                  smem[(4 * tid + 3) * 3 + (c)] = w4c##c.w; }
        L3M(WBW4)
#undef WBW4
        __syncthreads();
#pragma unroll
        for (int r2 = 0; r2 < 4; ++r2) {
            int r = t4 + r2;
            W4g[(size_t)r * 768 + c3 + 0] = smem[r * 3 + 0];
            W4g[(size_t)r * 768 + c3 + 1] = smem[r * 3 + 1];
            W4g[(size_t)r * 768 + c3 + 2] = smem[r * 3 + 2];
        }
    }
}

// ---------- final batch forward: fp32 tiled GEMM C = act(A@W + bias) ----------
__global__ __launch_bounds__(256) void k_gemm(const float* __restrict__ A,
                                              const float* __restrict__ W,
                                              const float* __restrict__ bias,
                                              float* __restrict__ C,
                                              int M, int N, int K, int do_relu) {
    __shared__ float sA[16][64];
    __shared__ float sB[16][128];
    int bn = blockIdx.x, bm = blockIdx.y;
    int m0 = bm * 64, n0 = bn * 128;
    int tid = threadIdx.x;
    int tx = tid & 31, ty = tid >> 5;
    float acc[8][4];
#pragma unroll
    for (int i = 0; i < 8; ++i)
#pragma unroll
        for (int j = 0; j < 4; ++j) acc[i][j] = 0.f;

    for (int kt = 0; kt < K; kt += 16) {
        {
            int r = tid >> 2, cc = (tid & 3) * 4;
            const float4 a4 = *(const float4*)(A + (size_t)(m0 + r) * K + kt + cc);
            sA[cc + 0][r] = a4.x; sA[cc + 1][r] = a4.y; sA[cc + 2][r] = a4.z; sA[cc + 3][r] = a4.w;
        }
        {
            int r = tid >> 5, cc = (tid & 31) * 4;
            *(float4*)(&sB[r][cc]) = *(const float4*)(W + (size_t)(kt + r) * N + n0 + cc);
            *(float4*)(&sB[r + 8][cc]) = *(const float4*)(W + (size_t)(kt + r + 8) * N + n0 + cc);
        }
        __syncthreads();
#pragma unroll
        for (int k = 0; k < 16; ++k) {
            float av[8];
#pragma unroll
            for (int i = 0; i < 8; ++i) av[i] = sA[k][ty * 8 + i];
            float bx = sB[k][tx * 4 + 0], by = sB[k][tx * 4 + 1];
            float bz = sB[k][tx * 4 + 2], bw = sB[k][tx * 4 + 3];
#pragma unroll
            for (int i = 0; i < 8; ++i) {
                acc[i][0] += av[i] * bx; acc[i][1] += av[i] * by;
                acc[i][2] += av[i] * bz; acc[i][3] += av[i] * bw;
            }
        }
        __syncthreads();
    }
    float bx = bias[n0 + tx * 4 + 0], by = bias[n0 + tx * 4 + 1];
    float bz = bias[n0 + tx * 4 + 2], bw = bias[n0 + tx * 4 + 3];
#pragma unroll
    for (int i = 0; i < 8; ++i) {
        int m = m0 + ty * 8 + i;
        float4 v;
        v.x = acc[i][0] + bx; v.y = acc[i][1] + by;
        v.z = acc[i][2] + bz; v.w = acc[i][3] + bw;
        if (do_relu) {
            v.x = fmaxf(v.x, 0.f); v.y = fmaxf(v.y, 0.f);
            v.z = fmaxf(v.z, 0.f); v.w = fmaxf(v.w, 0.f);
        }
        *(float4*)(C + (size_t)m * N + n0 + tx * 4) = v;
    }
}

__global__ __launch_bounds__(128) void k_colsum(const float* __restrict__ Y,
                                                float* __restrict__ out) {
    int c = blockIdx.x * 128 + threadIdx.x;
    int r0 = blockIdx.y * 128;
    float s = 0.f;
    for (int r = 0; r < 128; ++r) s += Y[(size_t)(r0 + r) * 768 + c];
    out[blockIdx.y * 768 + c] = s;
}

__global__ __launch_bounds__(768) void k_out(const float* __restrict__ msum,
                                             float* __restrict__ out) {
    int c = threadIdx.x;
    float s = 0.f;
#pragma unroll
    for (int i = 0; i < 32; ++i) s += msum[i * 768 + c];
    out[c] = s * (1.f / 4096.f);
}

extern "C" void kernel_launch(void* const* d_in, const int* in_sizes, int n_in,
                              void* d_out, int out_size, void* d_ws, size_t ws_size,
                              hipStream_t stream) {
    const float* x = (const float*)d_in[0];
    float* W1 = (float*)d_in[1];
    float* b1 = (float*)d_in[2];
    float* W2 = (float*)d_in[3];
    float* b2 = (float*)d_in[4];
    float* W3 = (float*)d_in[5];
    float* b3 = (float*)d_in[6];
    float* W4 = (float*)d_in[7];
    float* b4 = (float*)d_in[8];
    const int* flag = (const int*)d_in[9];
    float* wsf = (float*)d_ws;

    unsigned* bar = (unsigned*)(wsf + OFF_HA);
    k_zero<<<1, 1024, 0, stream>>>(bar);

    // entire 1024-step TTT scan: ONE persistent kernel, persistent-LDS broadcast cache
    k_scan<<<256, 512, 0, stream>>>(x, W1, b1, W2, b2, W3, b3, W4, b4, wsf, flag);

    // final forward over all 4096 tokens, chunked by 1024, + mean
    float* HA = wsf + OFF_HA;
    float* HB = wsf + OFF_HB;
    for (int ch = 0; ch < 4; ++ch) {
        const float* Xc = x + (size_t)ch * 1024 * 768;
        k_gemm<<<dim3(16, 16), 256, 0, stream>>>(Xc, W1, b1, HA, 1024, 2048, 768, 1);
        k_gemm<<<dim3(16, 16), 256, 0, stream>>>(HA, W2, b2, HB, 1024, 2048, 2048, 1);
        k_gemm<<<dim3(16, 16), 256, 0, stream>>>(HB, W3, b3, HA, 1024, 2048, 2048, 1);
        k_gemm<<<dim3(6, 16), 256, 0, stream>>>(HA, W4, b4, HB, 1024, 768, 2048, 0);
        k_colsum<<<dim3(6, 8), 128, 0, stream>>>(HB, wsf + OFF_MSUM + (size_t)ch * 8 * 768);
    }
    k_out<<<1, 768, 0, stream>>>(wsf + OFF_MSUM, (float*)d_out);
}